// Round 2
// baseline (529.540 us; speedup 1.0000x reference)
//
#include <hip/hip_runtime.h>
#include <hip/hip_bf16.h>

// Causal flash attention, B=4 H=16 S=2048 DK=DV=128, fp32 in/out, bf16 MFMA compute.
// Block = 512 threads (8 waves); wave owns 16 q rows (BM=128/block); KV tile = 64 keys.
// Pipelined: tile t+1 global->VGPR prefetch overlaps tile t compute.

#define S_LEN 2048
#define DKC   128
#define DVC   128
#define BM    128
#define BN    64
#define KPAD  136   // K LDS row stride (bf16): 272B -> b128-aligned reads, 2-way banks
#define VPAD  72    // Vt LDS row stride:      144B -> b128-aligned reads, 2-way banks
#define PPAD  72

typedef __bf16 bf16;
typedef bf16  bf16x4 __attribute__((ext_vector_type(4)));
typedef bf16  bf16x8 __attribute__((ext_vector_type(8)));
typedef float f32x4  __attribute__((ext_vector_type(4)));

__global__ __launch_bounds__(512, 4)
void fa_kernel(const float* __restrict__ Q, const float* __restrict__ K,
               const float* __restrict__ V, float* __restrict__ O) {
  __shared__ bf16 Klds[BN][KPAD];        // [key][d]
  __shared__ bf16 Vlds[DVC][VPAD];       // transposed: [dv][key]
  __shared__ bf16 Plds[8][16][PPAD];     // per-wave P staging [wave][q][key]

  const int tid  = threadIdx.x;
  const int w    = tid >> 6;             // 0..7
  const int lane = tid & 63;
  const int quad = lane >> 4;
  const int l16  = lane & 15;

  // XCD-aware swizzle; heavy (long-K) q-tiles dispatched first.
  const int lin   = blockIdx.x;          // 0..1023
  const int xcd   = lin & 7;
  const int idx   = lin >> 3;            // 0..127
  const int qtile = 15 - (idx & 15);     // 0..15
  const int bh    = xcd + 8 * (idx >> 4);

  const int q0 = qtile * BM;
  const size_t base = (size_t)bh * S_LEN * DKC;
  const float* Qp = Q + base;
  const float* Kp = K + base;
  const float* Vp = V + base;
  float*       Op = O + base;

  const float SCALE2 = 0.08838834764831845f * 1.4426950408889634f; // 1/sqrt(128)*log2e

  // ---- Q fragments (A layout): wave w owns rows q0 + w*16 .. +15 ----
  bf16x8 qf[4];
  {
    const int qg = q0 + w * 16 + l16;
    const float* qrow = Qp + (size_t)qg * DKC;
#pragma unroll
    for (int c = 0; c < 4; ++c) {
      const float* p = qrow + c * 32 + quad * 8;
      float4 x = *(const float4*)p;
      float4 y = *(const float4*)(p + 4);
      bf16x8 f;
      f[0] = (bf16)(x.x * SCALE2); f[1] = (bf16)(x.y * SCALE2);
      f[2] = (bf16)(x.z * SCALE2); f[3] = (bf16)(x.w * SCALE2);
      f[4] = (bf16)(y.x * SCALE2); f[5] = (bf16)(y.y * SCALE2);
      f[6] = (bf16)(y.z * SCALE2); f[7] = (bf16)(y.w * SCALE2);
      qf[c] = f;
    }
  }

  f32x4 oacc[8];
#pragma unroll
  for (int n = 0; n < 8; ++n)
#pragma unroll
    for (int r = 0; r < 4; ++r) oacc[n][r] = 0.0f;
  float mrow[4], lrow[4];
#pragma unroll
  for (int r = 0; r < 4; ++r) { mrow[r] = -1e30f; lrow[r] = 0.0f; }

  const int ntiles = q0 / BN + 2;            // block-level tile count
  const int my_nt  = q0 / BN + 1 + (w >> 2); // waves 0-3 need one fewer tile

  // staging assignment (512 threads, 4 float4 each for K and V)
  const int krow = tid >> 5;                 // 0..15
  const int kcol = (tid & 31) * 4;           // 0..124

  float4 kreg[4], vreg[4];
#define LOAD_TILE(KVB)                                                        \
  {                                                                           \
    _Pragma("unroll")                                                         \
    for (int i = 0; i < 4; ++i) {                                             \
      int r  = krow + i * 16;                                                 \
      kreg[i] = *(const float4*)(Kp + (size_t)((KVB) + r) * DKC + kcol);      \
      int k  = (tid & 31) + 32 * (i & 1);                                     \
      int d4 = ((tid >> 5) + 16 * (i >> 1)) * 4;                              \
      vreg[i] = *(const float4*)(Vp + (size_t)((KVB) + k) * DVC + d4);        \
    }                                                                         \
  }

  LOAD_TILE(0)

  for (int t = 0; t < ntiles; ++t) {
    const int kvb = t * BN;
    __syncthreads();  // all waves done reading previous K/V tile

    // ---- stage from prefetch regs -> LDS ----
#pragma unroll
    for (int i = 0; i < 4; ++i) {
      int r = krow + i * 16;
      bf16x4 k4;
      k4[0] = (bf16)kreg[i].x; k4[1] = (bf16)kreg[i].y;
      k4[2] = (bf16)kreg[i].z; k4[3] = (bf16)kreg[i].w;
      *(bf16x4*)&Klds[r][kcol] = k4;       // 8B packed write, 2-way banks
      int k  = (tid & 31) + 32 * (i & 1);
      int d4 = ((tid >> 5) + 16 * (i >> 1)) * 4;
      Vlds[d4 + 0][k] = (bf16)vreg[i].x;
      Vlds[d4 + 1][k] = (bf16)vreg[i].y;
      Vlds[d4 + 2][k] = (bf16)vreg[i].z;
      Vlds[d4 + 3][k] = (bf16)vreg[i].w;
    }
    __syncthreads();

    // ---- prefetch next tile (overlaps compute below) ----
    if (t + 1 < ntiles) LOAD_TILE(kvb + BN)

    if (t < my_nt) {
      // ---- S = Q K^T, fp32 accum ----
      f32x4 sacc[4];
#pragma unroll
      for (int n = 0; n < 4; ++n)
#pragma unroll
        for (int r = 0; r < 4; ++r) sacc[n][r] = 0.0f;
#pragma unroll
      for (int c = 0; c < 4; ++c) {
#pragma unroll
        for (int n = 0; n < 4; ++n) {
          bf16x8 kf = *(const bf16x8*)&Klds[n * 16 + l16][c * 32 + quad * 8];
          sacc[n] = __builtin_amdgcn_mfma_f32_16x16x32_bf16(qf[c], kf, sacc[n], 0, 0, 0);
        }
      }

      // ---- causal mask on this wave's diagonal tile ----
      if (t == my_nt - 1) {
#pragma unroll
        for (int n = 0; n < 4; ++n) {
          int kg = kvb + n * 16 + l16;
#pragma unroll
          for (int r = 0; r < 4; ++r) {
            int qg = q0 + w * 16 + quad * 4 + r;
            if (kg > qg) sacc[n][r] = -1e30f;
          }
        }
      }

      // ---- online softmax (base-2); exp result reuses sacc storage ----
#pragma unroll
      for (int r = 0; r < 4; ++r) {
        float mx = fmaxf(fmaxf(sacc[0][r], sacc[1][r]), fmaxf(sacc[2][r], sacc[3][r]));
        mx = fmaxf(mx, __shfl_xor(mx, 1));
        mx = fmaxf(mx, __shfl_xor(mx, 2));
        mx = fmaxf(mx, __shfl_xor(mx, 4));
        mx = fmaxf(mx, __shfl_xor(mx, 8));
        float mnew  = fmaxf(mrow[r], mx);
        float alpha = exp2f(mrow[r] - mnew);
        mrow[r] = mnew;
        float ps = 0.0f;
#pragma unroll
        for (int n = 0; n < 4; ++n) {
          float p = exp2f(sacc[n][r] - mnew);
          sacc[n][r] = p;
          ps += p;
        }
        lrow[r] = lrow[r] * alpha + ps;
#pragma unroll
        for (int n = 0; n < 8; ++n) oacc[n][r] *= alpha;
      }

      // ---- P: C-layout -> per-wave LDS -> A-layout (no barrier needed) ----
#pragma unroll
      for (int n = 0; n < 4; ++n)
#pragma unroll
        for (int r = 0; r < 4; ++r)
          Plds[w][quad * 4 + r][n * 16 + l16] = (bf16)sacc[n][r];

      // ---- O += P V ----
#pragma unroll
      for (int c = 0; c < 2; ++c) {
        bf16x8 pf = *(const bf16x8*)&Plds[w][l16][c * 32 + quad * 8];
#pragma unroll
        for (int n = 0; n < 8; ++n) {
          bf16x8 vf = *(const bf16x8*)&Vlds[n * 16 + l16][c * 32 + quad * 8];
          oacc[n] = __builtin_amdgcn_mfma_f32_16x16x32_bf16(pf, vf, oacc[n], 0, 0, 0);
        }
      }
    }
  }

  // ---- epilogue: reduce l across the 16-lane groups, normalize, store ----
  float linv[4];
#pragma unroll
  for (int r = 0; r < 4; ++r) {
    float s = lrow[r];
    s += __shfl_xor(s, 1);
    s += __shfl_xor(s, 2);
    s += __shfl_xor(s, 4);
    s += __shfl_xor(s, 8);
    linv[r] = 1.0f / s;
  }
#pragma unroll
  for (int n = 0; n < 8; ++n) {
#pragma unroll
    for (int r = 0; r < 4; ++r) {
      int qg = q0 + w * 16 + quad * 4 + r;
      Op[(size_t)qg * DVC + n * 16 + l16] = oacc[n][r] * linv[r];
    }
  }
}

extern "C" void kernel_launch(void* const* d_in, const int* in_sizes, int n_in,
                              void* d_out, int out_size, void* d_ws, size_t ws_size,
                              hipStream_t stream) {
  const float* Q = (const float*)d_in[0];
  const float* K = (const float*)d_in[1];
  const float* V = (const float*)d_in[2];
  // d_in[3] is the causal tril mask; causality is applied analytically.
  float* O = (float*)d_out;
  dim3 grid(1024);   // 64 bh * 16 q-tiles, XCD-swizzled in-kernel
  fa_kernel<<<grid, 512, 0, stream>>>(Q, K, V, O);
}